// Round 1
// baseline (20453.905 us; speedup 1.0000x reference)
//
#include <hip/hip_runtime.h>
#include <hip/hip_bf16.h>
#include <stdint.h>

// Problem constants
#define NB 128    // batch
#define NT 512    // time steps
#define ND 256    // input dim
#define NH 1024   // hidden dim
#define NZ 128    // latent dim
#define NG 4096   // 4*NH gate width
#define NK 1280   // ND + NH combined K

typedef __attribute__((ext_vector_type(8))) __bf16 bf16x8;
typedef __attribute__((ext_vector_type(4))) __bf16 bf16x4;
typedef __attribute__((ext_vector_type(4))) float floatx4;

__device__ __forceinline__ float sigmoidf_(float x) { return 1.0f / (1.0f + expf(-x)); }
__device__ __forceinline__ float softplusf_(float x) {
  return (x > 0.0f) ? (x + log1pf(expf(-x))) : log1pf(expf(x));
}

// ---------------------------------------------------------------------------
// Kernel 1: convert x (B,T,D) fp32 -> xb (T,B,D) bf16
// ---------------------------------------------------------------------------
__global__ __launch_bounds__(256) void convert_x_kernel(
    const float4* __restrict__ x, __bf16* __restrict__ xb) {
  int i = blockIdx.x * 256 + threadIdx.x;   // [0, B*T*D/4)
  int d4 = i & 63;                          // float4 index within row of 256
  int bt = i >> 6;                          // b*512 + t
  int b = bt >> 9;
  int t = bt & 511;
  float4 v = x[i];
  bf16x4 o;
  o[0] = (__bf16)v.x; o[1] = (__bf16)v.y; o[2] = (__bf16)v.z; o[3] = (__bf16)v.w;
  *(bf16x4*)(xb + ((t * NB + b) * ND + d4 * 4)) = o;
}

// ---------------------------------------------------------------------------
// Kernel 2: persistent LSTM.
// Grid 256 WGs x 512 thr (1 WG/CU, cooperative). WG = (m_blk = blockIdx&7,
// n_blk = blockIdx>>3): batch rows [m_blk*16, +16), h-cols [n_blk*32, +32).
// Each of 8 waves holds B-fragments (bf16 weights, K=1280 x 16 gate cols) in
// 160 persistent VGPRs. Group barrier = 32 monotonic slots per m_blk.
// ---------------------------------------------------------------------------
__global__ __launch_bounds__(512) void lstm_persistent(
    const __bf16* __restrict__ xb,    // (T, B, D) bf16
    const float* __restrict__ W,      // (D, 4H)
    const float* __restrict__ U,      // (H, 4H)
    const float* __restrict__ bias,   // (4H)
    __bf16* __restrict__ hbuf,        // 2 * B * H bf16 (double buffer)
    float* __restrict__ hlast,        // B * H fp32
    unsigned int* __restrict__ slots) // 256 barrier slots
{
  const int tid = threadIdx.x;
  const int wg = blockIdx.x;
  const int m_blk = wg & 7;
  const int n_blk = wg >> 3;
  const int wave = tid >> 6;
  const int lane = tid & 63;
  const int q = lane >> 4;     // k-quad
  const int n16 = lane & 15;   // MFMA col within tile
  const int g = wave >> 1;     // gate index 0..3 (i,f,g,o)
  const int half = wave & 1;   // which 16 of the 32 h-cols

  __shared__ __bf16 As[16 * 1288];  // A tile, rows padded 1280 -> 1288 (+16B)
  __shared__ float Gs[16][132];     // gates, padded 128 -> 132

  // ---- Load persistent B fragments: Wcomb[k][gc], k = ks*32 + q*8 + j ----
  const int gc = g * NH + n_blk * 32 + half * 16 + n16;  // global gate column
  bf16x8 Bf[40];
#pragma unroll
  for (int ks = 0; ks < 40; ++ks) {
    const float* src = (ks < 8) ? (W + (ks * 32) * NG + gc)
                                : (U + (ks * 32 - 256) * NG + gc);
    bf16x8 v;
#pragma unroll
    for (int j = 0; j < 8; ++j) v[j] = (__bf16)src[(q * 8 + j) * NG];
    Bf[ks] = v;
  }

  // ---- Elementwise-role constants: thread owns cell (r_e, c_e) ----
  const int r_e = tid >> 5;
  const int c_e = tid & 31;
  const int hcol = n_blk * 32 + c_e;   // [0, NH)
  const int grow = m_blk * 16 + r_e;   // [0, NB)
  const float bi = bias[hcol];
  const float bff = bias[NH + hcol];
  const float bg = bias[2 * NH + hcol];
  const float bo = bias[3 * NH + hcol];
  float c_state = 0.0f;

  const int slot_base = m_blk * 32;

  for (int t = 0; t < NT; ++t) {
    // ---- Stage A = [x_t | h_prev] (16 x 1280 bf16) into LDS ----
    {
      int r = tid >> 5, c = tid & 31;  // x: 512 chunks of 16B, one per thread
      bf16x8 xv = ((const bf16x8*)(xb + (t * NB + m_blk * 16 + r) * ND))[c];
      *(bf16x8*)(As + r * 1288 + c * 8) = xv;
      const __bf16* hsrc = hbuf + (t & 1) * (NB * NH);
#pragma unroll
      for (int it = 0; it < 4; ++it) {  // h: 2048 chunks, 4 per thread
        int idx = tid + it * 512;
        int hr = idx >> 7, hc = idx & 127;
        bf16x8 hv = ((const bf16x8*)(hsrc + (m_blk * 16 + hr) * NH))[hc];
        *(bf16x8*)(As + hr * 1288 + 256 + hc * 8) = hv;
      }
    }
    __syncthreads();

    // ---- MFMA: one 16x16 tile per wave, K=1280, two indep. acc chains ----
    floatx4 acc0 = {0.f, 0.f, 0.f, 0.f};
    floatx4 acc1 = {0.f, 0.f, 0.f, 0.f};
    const __bf16* arow = As + n16 * 1288 + q * 8;
#pragma unroll
    for (int ks = 0; ks < 40; ks += 2) {
      bf16x8 a0 = *(const bf16x8*)(arow + ks * 32);
      bf16x8 a1 = *(const bf16x8*)(arow + ks * 32 + 32);
      acc0 = __builtin_amdgcn_mfma_f32_16x16x32_bf16(a0, Bf[ks], acc0, 0, 0, 0);
      acc1 = __builtin_amdgcn_mfma_f32_16x16x32_bf16(a1, Bf[ks + 1], acc1, 0, 0, 0);
    }
    floatx4 acc = acc0 + acc1;

    // ---- Spill gate tile to LDS: D[m=q*4+rr][n=n16] ----
    {
      int colL = g * 32 + half * 16 + n16;
#pragma unroll
      for (int rr = 0; rr < 4; ++rr) Gs[q * 4 + rr][colL] = acc[rr];
    }
    __syncthreads();

    // ---- LSTM cell (fp32, exact nonlinearities) ----
    {
      float xi = Gs[r_e][c_e] + bi;
      float xf = Gs[r_e][32 + c_e] + bff;
      float xg = Gs[r_e][64 + c_e] + bg;
      float xo = Gs[r_e][96 + c_e] + bo;
      float iv = sigmoidf_(xi);
      float fv = sigmoidf_(xf);
      float gv = softplusf_(xg);
      float ov = sigmoidf_(xo);
      c_state = fv * c_state + iv * gv;
      float hv = ov * softplusf_(c_state);
      hbuf[((t + 1) & 1) * (NB * NH) + grow * NH + hcol] = (__bf16)hv;
      if (t == NT - 1) hlast[grow * NH + hcol] = hv;
    }

    if (t < NT - 1) {
      __syncthreads();  // drains vmcnt: all h stores complete in XCD L2
      if (tid == 0) {
        __threadfence();  // agent release: writes back dirty L2 to LLC
        __hip_atomic_store(&slots[slot_base + n_blk], (unsigned)(t + 1),
                           __ATOMIC_RELEASE, __HIP_MEMORY_SCOPE_AGENT);
      }
      if (tid < 32) {  // wave 0 polls all 32 group slots
        unsigned tgt = (unsigned)(t + 1);
        while (__hip_atomic_load(&slots[slot_base + tid], __ATOMIC_RELAXED,
                                 __HIP_MEMORY_SCOPE_AGENT) < tgt) {
          __builtin_amdgcn_s_sleep(1);
        }
      }
      __syncthreads();
      __threadfence();  // agent acquire: invalidate L1/L2 before reading h
    }
  }
}

// ---------------------------------------------------------------------------
// Kernel 3: projection head. 32 blocks x 128 thr; 4 batch rows per block.
// ---------------------------------------------------------------------------
__global__ __launch_bounds__(128) void proj_kernel(
    const float* __restrict__ hlast,
    const float* __restrict__ Wm, const float* __restrict__ bm,
    const float* __restrict__ Wv, const float* __restrict__ bv,
    const float* __restrict__ eps, float* __restrict__ out) {
  __shared__ float hs[4][NH];
  const int bb = blockIdx.x * 4;
  for (int idx = threadIdx.x; idx < 4 * NH; idx += 128)
    hs[idx >> 10][idx & (NH - 1)] = hlast[(bb + (idx >> 10)) * NH + (idx & (NH - 1))];
  __syncthreads();
  const int z = threadIdx.x;
  float am[4] = {0.f, 0.f, 0.f, 0.f};
  float av[4] = {0.f, 0.f, 0.f, 0.f};
#pragma unroll 8
  for (int k = 0; k < NH; ++k) {
    float wm = Wm[k * NZ + z];
    float wv = Wv[k * NZ + z];
#pragma unroll
    for (int r = 0; r < 4; ++r) {
      am[r] += hs[r][k] * wm;
      av[r] += hs[r][k] * wv;
    }
  }
#pragma unroll
  for (int r = 0; r < 4; ++r) {
    int b = bb + r;
    float mu = am[r] + bm[z];
    float lv = av[r] + bv[z];
    float zz = mu + eps[b * NZ + z] * expf(0.5f * lv);
    out[b * NZ + z] = mu;
    out[NB * NZ + b * NZ + z] = lv;
    out[2 * NB * NZ + b * NZ + z] = zz;
  }
}

// ---------------------------------------------------------------------------
extern "C" void kernel_launch(void* const* d_in, const int* in_sizes, int n_in,
                              void* d_out, int out_size, void* d_ws, size_t ws_size,
                              hipStream_t stream) {
  const float* x   = (const float*)d_in[0];
  const float* W   = (const float*)d_in[1];
  const float* U   = (const float*)d_in[2];
  const float* b   = (const float*)d_in[3];
  const float* Wm  = (const float*)d_in[4];
  const float* bm  = (const float*)d_in[5];
  const float* Wv  = (const float*)d_in[6];
  const float* bv  = (const float*)d_in[7];
  const float* eps = (const float*)d_in[8];

  // Workspace layout (needs ~34.6 MB):
  //   [0,       524288)   hbuf: 2 x B x H bf16
  //   [524288,  1048576)  hlast: B x H fp32
  //   [1048576, 1049600)  slots: 256 x u32 (padded to 4096)
  //   [1052672, +33.5MB)  xb: T x B x D bf16
  char* ws = (char*)d_ws;
  __bf16* hbuf = (__bf16*)ws;
  float* hlast = (float*)(ws + 524288);
  unsigned int* slots = (unsigned int*)(ws + 1048576);
  __bf16* xb = (__bf16*)(ws + 1048576 + 4096);

  hipMemsetAsync(hbuf, 0, NB * NH * sizeof(__bf16), stream);  // h_0 = 0
  hipMemsetAsync(slots, 0, 256 * sizeof(unsigned int), stream);

  convert_x_kernel<<<dim3((NB * NT * ND) / 4 / 256), dim3(256), 0, stream>>>(
      (const float4*)x, xb);

  void* args[] = {(void*)&xb, (void*)&W, (void*)&U, (void*)&b,
                  (void*)&hbuf, (void*)&hlast, (void*)&slots};
  hipLaunchCooperativeKernel(reinterpret_cast<void*>(lstm_persistent),
                             dim3(256), dim3(512), args, 0, stream);

  proj_kernel<<<dim3(32), dim3(128), 0, stream>>>(hlast, Wm, bm, Wv, bv, eps,
                                                  (float*)d_out);
}

// Round 2
// 4257.399 us; speedup vs baseline: 4.8043x; 4.8043x over previous
//
#include <hip/hip_runtime.h>
#include <hip/hip_bf16.h>
#include <stdint.h>

// Problem constants
#define NB 128    // batch
#define NT 512    // time steps
#define ND 256    // input dim
#define NH 1024   // hidden dim
#define NZ 128    // latent dim
#define NG 4096   // 4*NH gate width
#define NK 1280   // ND + NH combined K

typedef __attribute__((ext_vector_type(8))) __bf16 bf16x8;
typedef __attribute__((ext_vector_type(4))) __bf16 bf16x4;
typedef __attribute__((ext_vector_type(4))) float floatx4;

__device__ __forceinline__ float sigmoidf_(float x) { return 1.0f / (1.0f + expf(-x)); }
__device__ __forceinline__ float softplusf_(float x) {
  return (x > 0.0f) ? (x + log1pf(expf(-x))) : log1pf(expf(x));
}

// ---------------------------------------------------------------------------
// Kernel 1: convert x (B,T,D) fp32 -> xb (T,B,D) bf16
// ---------------------------------------------------------------------------
__global__ __launch_bounds__(256) void convert_x_kernel(
    const float4* __restrict__ x, __bf16* __restrict__ xb) {
  int i = blockIdx.x * 256 + threadIdx.x;   // [0, B*T*D/4)
  int d4 = i & 63;                          // float4 index within row of 256
  int bt = i >> 6;                          // b*512 + t
  int b = bt >> 9;
  int t = bt & 511;
  float4 v = x[i];
  bf16x4 o;
  o[0] = (__bf16)v.x; o[1] = (__bf16)v.y; o[2] = (__bf16)v.z; o[3] = (__bf16)v.w;
  *(bf16x4*)(xb + ((t * NB + b) * ND + d4 * 4)) = o;
}

// ---------------------------------------------------------------------------
// Kernel 2: persistent LSTM.
// Grid 256 WGs x 512 thr (1 WG/CU, cooperative). WG = (m_blk = blockIdx&7,
// n_blk = blockIdx>>3): batch rows [m_blk*16, +16), h-cols [n_blk*32, +32).
// Each of 8 waves holds B-fragments (bf16 weights, K=1280 x 16 gate cols) in
// 160 persistent VGPRs — __launch_bounds__(512,2) gives the 256-VGPR budget
// needed to keep them resident (512,(default)) capped at 128 and spilled!).
// Cross-WG h exchange + slot barrier use agent-scope atomics only (LLC-
// coherent by construction) — NO __threadfence, so L2 is never invalidated
// and xb stays L2-hot across steps.
// ---------------------------------------------------------------------------
__global__ __launch_bounds__(512, 2) void lstm_persistent(
    const __bf16* __restrict__ xb,    // (T, B, D) bf16
    const float* __restrict__ W,      // (D, 4H)
    const float* __restrict__ U,      // (H, 4H)
    const float* __restrict__ bias,   // (4H)
    __bf16* __restrict__ hbuf,        // 2 * B * H bf16 (double buffer)
    float* __restrict__ hlast,        // B * H fp32
    unsigned int* __restrict__ slots) // 256 barrier slots
{
  const int tid = threadIdx.x;
  const int wg = blockIdx.x;
  const int m_blk = wg & 7;
  const int n_blk = wg >> 3;
  const int wave = tid >> 6;
  const int lane = tid & 63;
  const int q = lane >> 4;     // k-quad
  const int n16 = lane & 15;   // MFMA col within tile
  const int g = wave >> 1;     // gate index 0..3 (i,f,g,o)
  const int half = wave & 1;   // which 16 of the 32 h-cols

  __shared__ __bf16 As[16 * 1288];  // A tile, rows padded 1280 -> 1288 (+16B)
  __shared__ float Gs[16][132];     // gates, padded 128 -> 132
  __shared__ __bf16 Hs[16][32];     // h output tile

  // ---- Load persistent B fragments: Wcomb[k][gc], k = ks*32 + q*8 + j ----
  const int gc = g * NH + n_blk * 32 + half * 16 + n16;  // global gate column
  bf16x8 Bf[40];
#pragma unroll
  for (int ks = 0; ks < 40; ++ks) {
    const float* src = (ks < 8) ? (W + (ks * 32) * NG + gc)
                                : (U + (ks * 32 - 256) * NG + gc);
    bf16x8 v;
#pragma unroll
    for (int j = 0; j < 8; ++j) v[j] = (__bf16)src[(q * 8 + j) * NG];
    Bf[ks] = v;
  }
  const float bgc = bias[gc];  // bias folded into accumulator init

  // ---- Elementwise-role constants: thread owns cell (r_e, c_e) ----
  const int r_e = tid >> 5;
  const int c_e = tid & 31;
  const int hcol = n_blk * 32 + c_e;   // [0, NH)
  const int grow = m_blk * 16 + r_e;   // [0, NB)
  float c_state = 0.0f;

  const int slot_base = m_blk * 32;

  for (int t = 0; t < NT; ++t) {
    // ---- Stage A = [x_t | h_prev] (16 x 1280 bf16) into LDS ----
    {
      int r = tid >> 5, c = tid & 31;  // x: 512 chunks of 16B, one per thread
      bf16x8 xv = ((const bf16x8*)(xb + (t * NB + m_blk * 16 + r) * ND))[c];
      *(bf16x8*)(As + r * 1288 + c * 8) = xv;
      // h: agent-scope coherent 8B loads (LLC), 4096 chunks, 8 per thread
      const __bf16* hsrc = hbuf + (t & 1) * (NB * NH);
#pragma unroll
      for (int it = 0; it < 8; ++it) {
        int idx = tid + it * 512;
        int hr = idx >> 8, hc = idx & 255;   // row, 8B-chunk within row
        unsigned long long v = __hip_atomic_load(
            (const unsigned long long*)(hsrc + (m_blk * 16 + hr) * NH) + hc,
            __ATOMIC_RELAXED, __HIP_MEMORY_SCOPE_AGENT);
        *(unsigned long long*)(As + hr * 1288 + 256 + hc * 4) = v;
      }
    }
    __syncthreads();

    // ---- MFMA: one 16x16 tile per wave, K=1280, two indep. acc chains ----
    floatx4 acc0 = {bgc, bgc, bgc, bgc};
    floatx4 acc1 = {0.f, 0.f, 0.f, 0.f};
    const __bf16* arow = As + n16 * 1288 + q * 8;
#pragma unroll
    for (int ks = 0; ks < 40; ks += 2) {
      bf16x8 a0 = *(const bf16x8*)(arow + ks * 32);
      bf16x8 a1 = *(const bf16x8*)(arow + ks * 32 + 32);
      acc0 = __builtin_amdgcn_mfma_f32_16x16x32_bf16(a0, Bf[ks], acc0, 0, 0, 0);
      acc1 = __builtin_amdgcn_mfma_f32_16x16x32_bf16(a1, Bf[ks + 1], acc1, 0, 0, 0);
    }
    floatx4 acc = acc0 + acc1;

    // ---- Spill gate tile to LDS: D[m=q*4+rr][n=n16] ----
    {
      int colL = g * 32 + half * 16 + n16;
#pragma unroll
      for (int rr = 0; rr < 4; ++rr) Gs[q * 4 + rr][colL] = acc[rr];
    }
    __syncthreads();

    // ---- LSTM cell (fp32, exact nonlinearities); bias already in gates ----
    {
      float xi = Gs[r_e][c_e];
      float xf = Gs[r_e][32 + c_e];
      float xg = Gs[r_e][64 + c_e];
      float xo = Gs[r_e][96 + c_e];
      float iv = sigmoidf_(xi);
      float fv = sigmoidf_(xf);
      float gv = softplusf_(xg);
      float ov = sigmoidf_(xo);
      c_state = fv * c_state + iv * gv;
      float hv = ov * softplusf_(c_state);
      Hs[r_e][c_e] = (__bf16)hv;
      if (t == NT - 1) hlast[grow * NH + hcol] = hv;
    }
    __syncthreads();  // Hs complete; also protects As before next staging

    if (t < NT - 1) {
      // ---- wave 0: publish h tile (16x32 bf16 = 128 x 8B, agent-coherent)
      if (tid < 64) {
        __bf16* hdst = hbuf + ((t + 1) & 1) * (NB * NH);
#pragma unroll
        for (int it = 0; it < 2; ++it) {
          int idx = tid + it * 64;          // 128 chunks of 8B
          int hr = idx >> 3, hc = idx & 7;  // row, 8B-chunk (32 cols = 8 chunks)
          unsigned long long v = *(const unsigned long long*)(&Hs[hr][hc * 4]);
          __hip_atomic_store(
              (unsigned long long*)(hdst + (m_blk * 16 + hr) * NH + n_blk * 32) + hc,
              v, __ATOMIC_RELAXED, __HIP_MEMORY_SCOPE_AGENT);
        }
      }
      if (tid == 0) {
        // release: orders the h stores (same wave, vmcnt-drained) before slot
        __hip_atomic_store(&slots[slot_base + n_blk], (unsigned)(t + 1),
                           __ATOMIC_RELEASE, __HIP_MEMORY_SCOPE_AGENT);
      }
      if (tid < 32) {  // wave 0 polls all 32 group slots
        unsigned tgt = (unsigned)(t + 1);
        while (__hip_atomic_load(&slots[slot_base + tid], __ATOMIC_RELAXED,
                                 __HIP_MEMORY_SCOPE_AGENT) < tgt) {
          __builtin_amdgcn_s_sleep(1);
        }
      }
      __syncthreads();  // all waves wait on wave 0's poll
    }
  }
}

// ---------------------------------------------------------------------------
// Kernel 3: projection head. 32 blocks x 128 thr; 4 batch rows per block.
// ---------------------------------------------------------------------------
__global__ __launch_bounds__(128) void proj_kernel(
    const float* __restrict__ hlast,
    const float* __restrict__ Wm, const float* __restrict__ bm,
    const float* __restrict__ Wv, const float* __restrict__ bv,
    const float* __restrict__ eps, float* __restrict__ out) {
  __shared__ float hs[4][NH];
  const int bb = blockIdx.x * 4;
  for (int idx = threadIdx.x; idx < 4 * NH; idx += 128)
    hs[idx >> 10][idx & (NH - 1)] = hlast[(bb + (idx >> 10)) * NH + (idx & (NH - 1))];
  __syncthreads();
  const int z = threadIdx.x;
  float am[4] = {0.f, 0.f, 0.f, 0.f};
  float av[4] = {0.f, 0.f, 0.f, 0.f};
#pragma unroll 8
  for (int k = 0; k < NH; ++k) {
    float wm = Wm[k * NZ + z];
    float wv = Wv[k * NZ + z];
#pragma unroll
    for (int r = 0; r < 4; ++r) {
      am[r] += hs[r][k] * wm;
      av[r] += hs[r][k] * wv;
    }
  }
#pragma unroll
  for (int r = 0; r < 4; ++r) {
    int b = bb + r;
    float mu = am[r] + bm[z];
    float lv = av[r] + bv[z];
    float zz = mu + eps[b * NZ + z] * expf(0.5f * lv);
    out[b * NZ + z] = mu;
    out[NB * NZ + b * NZ + z] = lv;
    out[2 * NB * NZ + b * NZ + z] = zz;
  }
}

// ---------------------------------------------------------------------------
extern "C" void kernel_launch(void* const* d_in, const int* in_sizes, int n_in,
                              void* d_out, int out_size, void* d_ws, size_t ws_size,
                              hipStream_t stream) {
  const float* x   = (const float*)d_in[0];
  const float* W   = (const float*)d_in[1];
  const float* U   = (const float*)d_in[2];
  const float* b   = (const float*)d_in[3];
  const float* Wm  = (const float*)d_in[4];
  const float* bm  = (const float*)d_in[5];
  const float* Wv  = (const float*)d_in[6];
  const float* bv  = (const float*)d_in[7];
  const float* eps = (const float*)d_in[8];

  // Workspace layout (needs ~34.6 MB):
  //   [0,       524288)   hbuf: 2 x B x H bf16
  //   [524288,  1048576)  hlast: B x H fp32
  //   [1048576, 1049600)  slots: 256 x u32 (padded to 4096)
  //   [1052672, +33.5MB)  xb: T x B x D bf16
  char* ws = (char*)d_ws;
  __bf16* hbuf = (__bf16*)ws;
  float* hlast = (float*)(ws + 524288);
  unsigned int* slots = (unsigned int*)(ws + 1048576);
  __bf16* xb = (__bf16*)(ws + 1048576 + 4096);

  hipMemsetAsync(hbuf, 0, NB * NH * sizeof(__bf16), stream);  // h_0 = 0
  hipMemsetAsync(slots, 0, 256 * sizeof(unsigned int), stream);

  convert_x_kernel<<<dim3((NB * NT * ND) / 4 / 256), dim3(256), 0, stream>>>(
      (const float4*)x, xb);

  void* args[] = {(void*)&xb, (void*)&W, (void*)&U, (void*)&b,
                  (void*)&hbuf, (void*)&hlast, (void*)&slots};
  hipLaunchCooperativeKernel(reinterpret_cast<void*>(lstm_persistent),
                             dim3(256), dim3(512), args, 0, stream);

  proj_kernel<<<dim3(32), dim3(128), 0, stream>>>(hlast, Wm, bm, Wv, bv, eps,
                                                  (float*)d_out);
}